// Round 2
// baseline (1257.637 us; speedup 1.0000x reference)
//
#include <hip/hip_runtime.h>
#include <hip/hip_bf16.h>
#include <stdint.h>

// Problem constants (all exact multiples of the tile sizes — no bounds checks)
#define M_DIM 4096      // 2*2048 rows of x
#define K_DIM 4096      // in_features
#define N_DIM 11008     // out_features
#define KW_DIM 2048     // weight_q words per row (each int32 holds 1 byte = 2 nibbles)

constexpr int BM = 128, BN = 128, BK = 64;
constexpr int LDK = BK + 8;   // padded LDS row stride: 144 B = 36 dwords -> 4-bank rotate, 16B aligned

typedef __bf16 bf16x8 __attribute__((ext_vector_type(8)));
typedef float  f32x4  __attribute__((ext_vector_type(4)));

__device__ inline unsigned int bf16_rne_bits(float f) {
    // fp32 -> bf16 with round-to-nearest-even, returned in low 16 bits
    unsigned int u = __float_as_uint(f);
    return (u + 0x7FFFu + ((u >> 16) & 1u)) >> 16;
}

__device__ inline unsigned int pack_bf16_pair(float lo, float hi) {
    // low 16 bits <- lo, high 16 bits <- hi (RNE)
    return bf16_rne_bits(lo) | (bf16_rne_bits(hi) << 16);
}

__global__ __launch_bounds__(256, 2)
void nf4_gemm_kernel(const float* __restrict__ X, const int* __restrict__ Wq,
                     const float* __restrict__ scale, const float* __restrict__ bias,
                     float* __restrict__ Out)
{
    __shared__ __align__(16) unsigned short As[BM * LDK];
    __shared__ __align__(16) unsigned short Bs[BN * LDK];
    __shared__ unsigned int lut2[256];   // byte -> packed (bf16 LUT[hi nibble], bf16 LUT[lo nibble])

    const int t = threadIdx.x;
    const int ntiles = N_DIM / BN;               // 86
    const int mtile = blockIdx.x / ntiles;
    const int ntile = blockIdx.x % ntiles;
    const int m0 = mtile * BM, n0 = ntile * BN;

    // --- build byte->bf16-pair LUT (one entry per thread, 256 threads) ---
    {
        const float LUT[16] = {-1.0f, -0.6961928f, -0.525073f, -0.39491748f,
                               -0.28444138f, -0.18477343f, -0.09105602f, 0.0f,
                               0.07958029f, 0.1609302f, 0.2461123f, 0.33791524f,
                               0.44070983f, 0.56261897f, 0.72295684f, 1.0f};
        // high nibble -> even k position (low 16 bits), low nibble -> odd k
        lut2[t] = pack_bf16_pair(LUT[(t >> 4) & 15], LUT[t & 15]);
    }

    // wave / lane decomposition: 4 waves in 2x2, each owns 64x64 (4x4 frags of 16x16)
    const int lane = t & 63;
    const int wv = t >> 6;
    const int wr = wv >> 1, wc = wv & 1;
    const int l16 = lane & 15, quad = lane >> 4;

    // staging coordinates
    const int a_r = t >> 4;          // 0..15, rows a_r + 16*i
    const int a_c = (t & 15) * 4;    // float column within BK
    const int b_r = t >> 3;          // 0..31, rows b_r + 32*i
    const int b_c = (t & 7) * 4;     // int32-word column within BK/2

    const float* aptr = X + (m0 + a_r) * K_DIM + a_c;
    const int*   bptr = Wq + (n0 + b_r) * KW_DIM + b_c;

    f32x4 acc[4][4];
    #pragma unroll
    for (int i = 0; i < 4; ++i)
        #pragma unroll
        for (int j = 0; j < 4; ++j)
            acc[i][j] = f32x4{0.f, 0.f, 0.f, 0.f};

    for (int kt = 0; kt < K_DIM / BK; ++kt) {
        // issue global loads before the barrier (overlap with prior compute)
        float4 av[8];
        int4   bv[4];
        #pragma unroll
        for (int i = 0; i < 8; ++i)
            av[i] = *reinterpret_cast<const float4*>(aptr + i * 16 * K_DIM);
        #pragma unroll
        for (int i = 0; i < 4; ++i)
            bv[i] = *reinterpret_cast<const int4*>(bptr + i * 32 * KW_DIM);
        aptr += BK;
        bptr += BK / 2;

        __syncthreads();   // prior iter's frag reads (and iter0: LUT build) complete

        // A: fp32 -> bf16 pack, 8B LDS stores
        #pragma unroll
        for (int i = 0; i < 8; ++i) {
            uint2 p;
            p.x = pack_bf16_pair(av[i].x, av[i].y);
            p.y = pack_bf16_pair(av[i].z, av[i].w);
            *reinterpret_cast<uint2*>(&As[(a_r + i * 16) * LDK + a_c]) = p;
        }
        // B: byte -> packed bf16 pair via LDS LUT, 16B LDS stores
        #pragma unroll
        for (int i = 0; i < 4; ++i) {
            uint4 q;
            q.x = lut2[bv[i].x & 255];
            q.y = lut2[bv[i].y & 255];
            q.z = lut2[bv[i].z & 255];
            q.w = lut2[bv[i].w & 255];
            *reinterpret_cast<uint4*>(&Bs[(b_r + i * 32) * LDK + b_c * 2]) = q;
        }
        __syncthreads();

        // compute: 2 k-steps of 32, 16 MFMAs each
        #pragma unroll
        for (int ks = 0; ks < 2; ++ks) {
            bf16x8 af[4], bfr[4];
            const int kb = ks * 32 + quad * 8;
            #pragma unroll
            for (int i = 0; i < 4; ++i)
                af[i] = *reinterpret_cast<const bf16x8*>(&As[(wr * 64 + i * 16 + l16) * LDK + kb]);
            #pragma unroll
            for (int j = 0; j < 4; ++j)
                bfr[j] = *reinterpret_cast<const bf16x8*>(&Bs[(wc * 64 + j * 16 + l16) * LDK + kb]);
            #pragma unroll
            for (int i = 0; i < 4; ++i)
                #pragma unroll
                for (int j = 0; j < 4; ++j)
                    acc[i][j] = __builtin_amdgcn_mfma_f32_16x16x32_bf16(af[i], bfr[j], acc[i][j], 0, 0, 0);
        }
    }

    // epilogue: out[m][n] = acc * scale[n] + bias[n]
    // C/D frag: col = lane&15 (n), row = quad*4 + reg (m)
    #pragma unroll
    for (int j = 0; j < 4; ++j) {
        const int n = n0 + wc * 64 + j * 16 + l16;
        const float s  = scale[n];
        const float bz = bias[n];
        #pragma unroll
        for (int i = 0; i < 4; ++i) {
            const int m = m0 + wr * 64 + i * 16 + quad * 4;
            float* op = Out + (size_t)m * N_DIM + n;
            #pragma unroll
            for (int r = 0; r < 4; ++r)
                op[(size_t)r * N_DIM] = acc[i][j][r] * s + bz;
        }
    }
}

extern "C" void kernel_launch(void* const* d_in, const int* in_sizes, int n_in,
                              void* d_out, int out_size, void* d_ws, size_t ws_size,
                              hipStream_t stream) {
    const float* X     = (const float*)d_in[0];
    const int*   Wq    = (const int*)d_in[1];
    const float* scale = (const float*)d_in[2];
    const float* bias  = (const float*)d_in[3];
    float* Out = (float*)d_out;

    dim3 grid((M_DIM / BM) * (N_DIM / BN));  // 32 * 86 = 2752 blocks
    nf4_gemm_kernel<<<grid, 256, 0, stream>>>(X, Wq, scale, bias, Out);
}

// Round 3
// 766.765 us; speedup vs baseline: 1.6402x; 1.6402x over previous
//
#include <hip/hip_runtime.h>
#include <stdint.h>

// Problem constants (exact multiples of tile sizes — no bounds checks)
#define M_DIM 4096      // 2*2048 rows of x
#define K_DIM 4096      // in_features
#define N_DIM 11008     // out_features
#define KW_DIM 2048     // weight_q words per row (each int32 holds 1 byte = 2 nibbles)

constexpr int BM = 128, BN = 128, BK = 64;

typedef __bf16 bf16x8 __attribute__((ext_vector_type(8)));
typedef float  f32x4  __attribute__((ext_vector_type(4)));

typedef __attribute__((address_space(1))) const void gv_t;  // global
typedef __attribute__((address_space(3))) void lv_t;        // LDS

__device__ inline unsigned int bf16_rne_bits(float f) {
    unsigned int u = __float_as_uint(f);
    return (u + 0x7FFFu + ((u >> 16) & 1u)) >> 16;
}
__device__ inline unsigned int pack_bf16_pair(float lo, float hi) {
    // low 16 bits <- lo (even k), high 16 bits <- hi (odd k)
    return bf16_rne_bits(lo) | (bf16_rne_bits(hi) << 16);
}

#define NF4_INIT  {-1.0f, -0.6961928f, -0.525073f, -0.39491748f, \
                   -0.28444138f, -0.18477343f, -0.09105602f, 0.0f, \
                   0.07958029f, 0.1609302f, 0.2461123f, 0.33791524f, \
                   0.44070983f, 0.56261897f, 0.72295684f, 1.0f}

// ---------------- Pass 1a: dequantize Wq (int32 words, 1 byte each) -> bf16 ----------------
// Bank-replicated LUT: lutr[entry*32 + copy]; lane l uses copy l&31 -> always bank l&31,
// worst case 2-way (lane l vs l+32) which is free (m136).
__global__ __launch_bounds__(256)
void dequant_w(const int4* __restrict__ Wq4, uint4* __restrict__ Wb4)
{
    __shared__ unsigned int lutr[256 * 32];
    const int t = threadIdx.x;
    {
        const float LUT[16] = NF4_INIT;
        const int c0 = t & 31;
        #pragma unroll
        for (int j = 0; j < 32; ++j) {
            const int e = (t >> 5) * 32 + j;   // 8 thread-groups x 32 entries = 256
            lutr[e * 32 + c0] = pack_bf16_pair(LUT[(e >> 4) & 15], LUT[e & 15]);
        }
    }
    __syncthreads();
    const int c = t & 31;
    size_t gid = (size_t)blockIdx.x * 256 + t;           // 2752*256 threads
    const size_t stride = 2752u * 256u;                  // x8 iters = 5,636,096 int4 groups exactly
    #pragma unroll
    for (int it = 0; it < 8; ++it) {
        int4 w = Wq4[gid];
        uint4 o;
        o.x = lutr[(w.x & 255) * 32 + c];
        o.y = lutr[(w.y & 255) * 32 + c];
        o.z = lutr[(w.z & 255) * 32 + c];
        o.w = lutr[(w.w & 255) * 32 + c];
        Wb4[gid] = o;
        gid += stride;
    }
}

// ---------------- Pass 1b: X fp32 -> bf16 ----------------
__global__ __launch_bounds__(256)
void convert_x(const float4* __restrict__ X4, uint4* __restrict__ Xb4)
{
    size_t gid = (size_t)blockIdx.x * 256 + threadIdx.x;  // 8192*256 = 2,097,152 = 16.78M/8
    float4 a = X4[gid * 2];
    float4 b = X4[gid * 2 + 1];
    uint4 o;
    o.x = pack_bf16_pair(a.x, a.y);
    o.y = pack_bf16_pair(a.z, a.w);
    o.z = pack_bf16_pair(b.x, b.y);
    o.w = pack_bf16_pair(b.z, b.w);
    Xb4[gid] = o;
}

// ---------------- Pass 2: bf16 GEMM, m97 structure (global_load_lds width=16) ----------------
__global__ __launch_bounds__(256, 2)
void gemm_bf16(const unsigned short* __restrict__ Xb, const unsigned short* __restrict__ Wb,
               const float* __restrict__ scale, const float* __restrict__ bias,
               float* __restrict__ Out)
{
    // unpadded: global_load_lds requires contiguous lane order (no padding allowed).
    // row stride 64 bf16 = 128 B; ds_read_b128 frag reads alias 2-way (free, m136).
    __shared__ __align__(16) unsigned short As[BM * BK];
    __shared__ __align__(16) unsigned short Bs[BN * BK];

    const int t = threadIdx.x;
    const int ntiles = N_DIM / BN;               // 86
    const int mtile = blockIdx.x / ntiles;
    const int ntile = blockIdx.x % ntiles;
    const int m0 = mtile * BM, n0 = ntile * BN;

    const int lane = t & 63;
    const int wv = t >> 6;
    const int wr = wv >> 1, wc = wv & 1;
    const int l16 = lane & 15, quad = lane >> 4;

    // staging: issue i covers rows i*32 + (t>>3), cols (t&7)*8 (bf16 elems), 16 B/lane
    const int s_row = t >> 3;
    const int s_col = (t & 7) * 8;
    const unsigned short* ap = Xb + (size_t)(m0 + s_row) * K_DIM + s_col;
    const unsigned short* bp = Wb + (size_t)(n0 + s_row) * K_DIM + s_col;
    char* as_dst = (char*)As + t * 16;   // + i*4096
    char* bs_dst = (char*)Bs + t * 16;

    f32x4 acc[4][4];
    #pragma unroll
    for (int i = 0; i < 4; ++i)
        #pragma unroll
        for (int j = 0; j < 4; ++j)
            acc[i][j] = f32x4{0.f, 0.f, 0.f, 0.f};

    for (int kt = 0; kt < K_DIM / BK; ++kt) {
        #pragma unroll
        for (int i = 0; i < 4; ++i)
            __builtin_amdgcn_global_load_lds((gv_t*)(ap + (size_t)i * 32 * K_DIM),
                                             (lv_t*)(as_dst + i * 4096), 16, 0, 0);
        #pragma unroll
        for (int i = 0; i < 4; ++i)
            __builtin_amdgcn_global_load_lds((gv_t*)(bp + (size_t)i * 32 * K_DIM),
                                             (lv_t*)(bs_dst + i * 4096), 16, 0, 0);
        ap += BK;
        bp += BK;
        __syncthreads();   // drains vmcnt: staged data visible

        #pragma unroll
        for (int ks = 0; ks < 2; ++ks) {
            bf16x8 af[4], bfr[4];
            const int kb = ks * 32 + quad * 8;
            #pragma unroll
            for (int i = 0; i < 4; ++i)
                af[i] = *reinterpret_cast<const bf16x8*>(&As[(wr * 64 + i * 16 + l16) * BK + kb]);
            #pragma unroll
            for (int j = 0; j < 4; ++j)
                bfr[j] = *reinterpret_cast<const bf16x8*>(&Bs[(wc * 64 + j * 16 + l16) * BK + kb]);
            #pragma unroll
            for (int i = 0; i < 4; ++i)
                #pragma unroll
                for (int j = 0; j < 4; ++j)
                    acc[i][j] = __builtin_amdgcn_mfma_f32_16x16x32_bf16(af[i], bfr[j], acc[i][j], 0, 0, 0);
        }
        __syncthreads();   // frag reads done before next iter's staging overwrites
    }

    // epilogue: out[m][n] = acc * scale[n] + bias[n]
    // C/D frag: col = lane&15 (n), row = quad*4 + reg (m)
    #pragma unroll
    for (int j = 0; j < 4; ++j) {
        const int n = n0 + wc * 64 + j * 16 + l16;
        const float s  = scale[n];
        const float bz = bias[n];
        #pragma unroll
        for (int i = 0; i < 4; ++i) {
            const int m = m0 + wr * 64 + i * 16 + quad * 4;
            float* op = Out + (size_t)m * N_DIM + n;
            #pragma unroll
            for (int r = 0; r < 4; ++r)
                op[(size_t)r * N_DIM] = acc[i][j][r] * s + bz;
        }
    }
}

// ---------------- Fallback: fused single-pass kernel (ws too small) ----------------
constexpr int F_LDK = BK + 8;
__global__ __launch_bounds__(256, 2)
void nf4_gemm_fused(const float* __restrict__ X, const int* __restrict__ Wq,
                    const float* __restrict__ scale, const float* __restrict__ bias,
                    float* __restrict__ Out)
{
    __shared__ __align__(16) unsigned short As[BM * F_LDK];
    __shared__ __align__(16) unsigned short Bs[BN * F_LDK];
    __shared__ unsigned int lut2[256];

    const int t = threadIdx.x;
    const int ntiles = N_DIM / BN;
    const int mtile = blockIdx.x / ntiles;
    const int ntile = blockIdx.x % ntiles;
    const int m0 = mtile * BM, n0 = ntile * BN;

    {
        const float LUT[16] = NF4_INIT;
        lut2[t] = pack_bf16_pair(LUT[(t >> 4) & 15], LUT[t & 15]);
    }

    const int lane = t & 63;
    const int wv = t >> 6;
    const int wr = wv >> 1, wc = wv & 1;
    const int l16 = lane & 15, quad = lane >> 4;

    const int a_r = t >> 4, a_c = (t & 15) * 4;
    const int b_r = t >> 3, b_c = (t & 7) * 4;

    const float* aptr = X + (m0 + a_r) * K_DIM + a_c;
    const int*   bptr = Wq + (n0 + b_r) * KW_DIM + b_c;

    f32x4 acc[4][4];
    #pragma unroll
    for (int i = 0; i < 4; ++i)
        #pragma unroll
        for (int j = 0; j < 4; ++j)
            acc[i][j] = f32x4{0.f, 0.f, 0.f, 0.f};

    for (int kt = 0; kt < K_DIM / BK; ++kt) {
        float4 av[8];
        int4   bv[4];
        #pragma unroll
        for (int i = 0; i < 8; ++i)
            av[i] = *reinterpret_cast<const float4*>(aptr + i * 16 * K_DIM);
        #pragma unroll
        for (int i = 0; i < 4; ++i)
            bv[i] = *reinterpret_cast<const int4*>(bptr + i * 32 * KW_DIM);
        aptr += BK;
        bptr += BK / 2;

        __syncthreads();

        #pragma unroll
        for (int i = 0; i < 8; ++i) {
            uint2 p;
            p.x = pack_bf16_pair(av[i].x, av[i].y);
            p.y = pack_bf16_pair(av[i].z, av[i].w);
            *reinterpret_cast<uint2*>(&As[(a_r + i * 16) * F_LDK + a_c]) = p;
        }
        #pragma unroll
        for (int i = 0; i < 4; ++i) {
            uint4 q;
            q.x = lut2[bv[i].x & 255];
            q.y = lut2[bv[i].y & 255];
            q.z = lut2[bv[i].z & 255];
            q.w = lut2[bv[i].w & 255];
            *reinterpret_cast<uint4*>(&Bs[(b_r + i * 32) * F_LDK + b_c * 2]) = q;
        }
        __syncthreads();

        #pragma unroll
        for (int ks = 0; ks < 2; ++ks) {
            bf16x8 af[4], bfr[4];
            const int kb = ks * 32 + quad * 8;
            #pragma unroll
            for (int i = 0; i < 4; ++i)
                af[i] = *reinterpret_cast<const bf16x8*>(&As[(wr * 64 + i * 16 + l16) * F_LDK + kb]);
            #pragma unroll
            for (int j = 0; j < 4; ++j)
                bfr[j] = *reinterpret_cast<const bf16x8*>(&Bs[(wc * 64 + j * 16 + l16) * F_LDK + kb]);
            #pragma unroll
            for (int i = 0; i < 4; ++i)
                #pragma unroll
                for (int j = 0; j < 4; ++j)
                    acc[i][j] = __builtin_amdgcn_mfma_f32_16x16x32_bf16(af[i], bfr[j], acc[i][j], 0, 0, 0);
        }
    }

    #pragma unroll
    for (int j = 0; j < 4; ++j) {
        const int n = n0 + wc * 64 + j * 16 + l16;
        const float s  = scale[n];
        const float bz = bias[n];
        #pragma unroll
        for (int i = 0; i < 4; ++i) {
            const int m = m0 + wr * 64 + i * 16 + quad * 4;
            float* op = Out + (size_t)m * N_DIM + n;
            #pragma unroll
            for (int r = 0; r < 4; ++r)
                op[(size_t)r * N_DIM] = acc[i][j][r] * s + bz;
        }
    }
}

extern "C" void kernel_launch(void* const* d_in, const int* in_sizes, int n_in,
                              void* d_out, int out_size, void* d_ws, size_t ws_size,
                              hipStream_t stream) {
    const float* X     = (const float*)d_in[0];
    const int*   Wq    = (const int*)d_in[1];
    const float* scale = (const float*)d_in[2];
    const float* bias  = (const float*)d_in[3];
    float* Out = (float*)d_out;

    const size_t WB_BYTES = (size_t)N_DIM * K_DIM * 2;   // 90,177,536
    const size_t XB_BYTES = (size_t)M_DIM * K_DIM * 2;   // 33,554,432

    if (ws_size >= WB_BYTES + XB_BYTES) {
        unsigned short* Wb = (unsigned short*)d_ws;
        unsigned short* Xb = (unsigned short*)((char*)d_ws + WB_BYTES);
        dequant_w<<<2752, 256, 0, stream>>>((const int4*)Wq, (uint4*)Wb);
        convert_x<<<8192, 256, 0, stream>>>((const float4*)X, (uint4*)Xb);
        gemm_bf16<<<(M_DIM / BM) * (N_DIM / BN), 256, 0, stream>>>(Xb, Wb, scale, bias, Out);
    } else {
        nf4_gemm_fused<<<(M_DIM / BM) * (N_DIM / BN), 256, 0, stream>>>(X, Wq, scale, bias, Out);
    }
}